// Round 1
// baseline (1586.606 us; speedup 1.0000x reference)
//
#include <hip/hip_runtime.h>
#include <hip/hip_bf16.h>
#include <math.h>

// ---------------------------------------------------------------------------
// MoCo contrastive: loss + queue update.
// B=1024 D=2048 H=1024 M=256 Q=65536 NNEG=16384, T=0.07
// All math fp32 this round (correctness baseline). GEMMs: 64x64 tile, 4x4
// micro, LDS padded +1 (naive transposed-A store is a 16-way bank conflict).
// Loss: logits bounded by 1/T (unit vectors) -> single-pass sum-exp, no max.
// ---------------------------------------------------------------------------

#define TS 64
#define KS 16

__global__ __launch_bounds__(256) void gemm_f32(const float* __restrict__ A,
                                                const float* __restrict__ B,
                                                float* __restrict__ C,
                                                int M_, int N_, int K_) {
    __shared__ float As[KS][TS + 1];  // As[kk][m]
    __shared__ float Bs[KS][TS + 1];  // Bs[kk][n]
    const int t  = threadIdx.x;
    const int tx = t & 15, ty = t >> 4;
    const int row0 = blockIdx.y * TS, col0 = blockIdx.x * TS;
    float acc[4][4] = {};

    for (int k0 = 0; k0 < K_; k0 += KS) {
#pragma unroll
        for (int i = 0; i < 4; ++i) {
            int idx = t + i * 256;            // 0..1023
            int m  = idx >> 4, kk = idx & 15; // A tile 64x16, kk fastest
            float v = 0.f;
            int gr = row0 + m, gc = k0 + kk;
            if (gr < M_ && gc < K_) v = A[(size_t)gr * K_ + gc];
            As[kk][m] = v;
            int n = idx & 63, kb = idx >> 6;  // B tile 16x64, n fastest
            float w = 0.f;
            int br = k0 + kb, bc = col0 + n;
            if (br < K_ && bc < N_) w = B[(size_t)br * N_ + bc];
            Bs[kb][n] = w;
        }
        __syncthreads();
#pragma unroll
        for (int kk = 0; kk < KS; ++kk) {
            float a[4], b[4];
#pragma unroll
            for (int i = 0; i < 4; ++i) a[i] = As[kk][ty * 4 + i];
#pragma unroll
            for (int j = 0; j < 4; ++j) b[j] = Bs[kk][tx * 4 + j];
#pragma unroll
            for (int i = 0; i < 4; ++i)
#pragma unroll
                for (int j = 0; j < 4; ++j) acc[i][j] += a[i] * b[j];
        }
        __syncthreads();
    }
#pragma unroll
    for (int i = 0; i < 4; ++i) {
        int gr = row0 + ty * 4 + i;
        if (gr >= M_) continue;
#pragma unroll
        for (int j = 0; j < 4; ++j) {
            int gc = col0 + tx * 4 + j;
            if (gc < N_) C[(size_t)gr * N_ + gc] = acc[i][j];
        }
    }
}

// in-place row l2norm, C==256, one block per row
__global__ __launch_bounds__(256) void row_l2norm(float* __restrict__ X, int C_) {
    const int r = blockIdx.x, t = threadIdx.x;
    float v = X[(size_t)r * C_ + t];
    __shared__ float s[256];
    s[t] = v * v;
    __syncthreads();
    for (int off = 128; off > 0; off >>= 1) {
        if (t < off) s[t] += s[t + off];
        __syncthreads();
    }
    float n = fmaxf(sqrtf(s[0]), 1e-12f);
    X[(size_t)r * C_ + t] = v / n;
}

// neg[j] = l2norm(queue[sidx[j]]), C==256
__global__ __launch_bounds__(256) void gather_norm(const float* __restrict__ queue,
                                                   const int* __restrict__ sidx,
                                                   float* __restrict__ neg, int C_) {
    const int r = blockIdx.x, t = threadIdx.x;
    const float* src = queue + (size_t)sidx[r] * C_;
    float v = src[t];
    __shared__ float s[256];
    s[t] = v * v;
    __syncthreads();
    for (int off = 128; off > 0; off >>= 1) {
        if (t < off) s[t] += s[t + off];
        __syncthreads();
    }
    float n = fmaxf(sqrtf(s[0]), 1e-12f);
    neg[(size_t)r * C_ + t] = v / n;
}

// pos[i] = dot(q_i,k_i)/T ; sumexp[i] = exp(pos[i])  (accumulator init)
__global__ __launch_bounds__(256) void pos_init(const float* __restrict__ q,
                                                const float* __restrict__ k,
                                                float* __restrict__ pos,
                                                float* __restrict__ sumexp,
                                                int C_, float invT) {
    const int r = blockIdx.x, t = threadIdx.x;
    float v = q[(size_t)r * C_ + t] * k[(size_t)r * C_ + t];
    __shared__ float s[256];
    s[t] = v;
    __syncthreads();
    for (int off = 128; off > 0; off >>= 1) {
        if (t < off) s[t] += s[t + off];
        __syncthreads();
    }
    if (t == 0) {
        float p = s[0] * invT;
        pos[r]    = p;
        sumexp[r] = expf(p);
    }
}

// fused q @ neg^T -> exp -> per-row sum, atomicAdd into sumexp.
// NT gemm: both operands K-contiguous. Requires B_%64==0, NNEG_%64==0.
__global__ __launch_bounds__(256) void logits_sumexp(const float* __restrict__ q,
                                                     const float* __restrict__ neg,
                                                     float* __restrict__ sumexp,
                                                     int B_, int NNEG_, int K_,
                                                     float invT) {
    __shared__ float As[KS][TS + 1];
    __shared__ float Ns[KS][TS + 1];
    const int t  = threadIdx.x;
    const int tx = t & 15, ty = t >> 4;
    const int row0 = blockIdx.y * TS, col0 = blockIdx.x * TS;
    float acc[4][4] = {};

    for (int k0 = 0; k0 < K_; k0 += KS) {
#pragma unroll
        for (int i = 0; i < 4; ++i) {
            int idx = t + i * 256;
            int m  = idx >> 4, kk = idx & 15;
            As[kk][m] = q[(size_t)(row0 + m) * K_ + (k0 + kk)];
            Ns[kk][m] = neg[(size_t)(col0 + m) * K_ + (k0 + kk)];
        }
        __syncthreads();
#pragma unroll
        for (int kk = 0; kk < KS; ++kk) {
            float a[4], b[4];
#pragma unroll
            for (int i = 0; i < 4; ++i) a[i] = As[kk][ty * 4 + i];
#pragma unroll
            for (int j = 0; j < 4; ++j) b[j] = Ns[kk][tx * 4 + j];
#pragma unroll
            for (int i = 0; i < 4; ++i)
#pragma unroll
                for (int j = 0; j < 4; ++j) acc[i][j] += a[i] * b[j];
        }
        __syncthreads();
    }
    // exp + per-row partial sums, reduce across tx, one atomic per row
    __shared__ float red[TS][17];
#pragma unroll
    for (int i = 0; i < 4; ++i) {
        float p = 0.f;
#pragma unroll
        for (int j = 0; j < 4; ++j) p += expf(acc[i][j] * invT);
        red[ty * 4 + i][tx] = p;
    }
    __syncthreads();
    if (t < TS) {
        float s = 0.f;
#pragma unroll
        for (int x = 0; x < 16; ++x) s += red[t][x];
        atomicAdd(&sumexp[row0 + t], s);
    }
}

// new_queue[widx[i]] = k[i], C==256
__global__ __launch_bounds__(256) void scatter_k(const float* __restrict__ k,
                                                 const int* __restrict__ widx,
                                                 float* __restrict__ newq, int C_) {
    const int r = blockIdx.x, t = threadIdx.x;
    newq[(size_t)widx[r] * C_ + t] = k[(size_t)r * C_ + t];
}

// loss = mean(log(sumexp) - pos)
__global__ __launch_bounds__(256) void final_loss(const float* __restrict__ pos,
                                                  const float* __restrict__ sumexp,
                                                  float* __restrict__ out, int B_) {
    const int t = threadIdx.x;
    float acc = 0.f;
    for (int i = t; i < B_; i += 256) acc += logf(sumexp[i]) - pos[i];
    __shared__ float s[256];
    s[t] = acc;
    __syncthreads();
    for (int off = 128; off > 0; off >>= 1) {
        if (t < off) s[t] += s[t + off];
        __syncthreads();
    }
    if (t == 0) out[0] = s[0] / (float)B_;
}

extern "C" void kernel_launch(void* const* d_in, const int* in_sizes, int n_in,
                              void* d_out, int out_size, void* d_ws, size_t ws_size,
                              hipStream_t stream) {
    const float* y1    = (const float*)d_in[0];
    const float* y2    = (const float*)d_in[1];
    const float* Wq    = (const float*)d_in[2];
    const float* Wk    = (const float*)d_in[3];
    const float* Wp    = (const float*)d_in[4];
    const float* queue = (const float*)d_in[5];
    const int*   sidx  = (const int*)d_in[6];
    const int*   widx  = (const int*)d_in[7];
    float* out = (float*)d_out;

    const int B    = in_sizes[7];              // 1024
    const int NNEG = in_sizes[6];              // 16384
    const int D    = in_sizes[0] / B;          // 2048
    const int H    = in_sizes[2] / D;          // 1024
    const int M    = in_sizes[4] / H;          // 256
    const int Q    = in_sizes[5] / M;          // 65536
    const float invT = 1.0f / 0.07f;

    // workspace layout (floats)
    float* ws = (float*)d_ws;
    float* T1     = ws;                         // B*H
    float* T2     = T1 + (size_t)B * H;         // B*H
    float* qbuf   = T2 + (size_t)B * H;         // B*M
    float* kbuf   = qbuf + (size_t)B * M;       // B*M  (adjacent to qbuf!)
    float* negbuf = kbuf + (size_t)B * M;       // NNEG*M
    float* pos    = negbuf + (size_t)NNEG * M;  // B
    float* sumexp = pos + B;                    // B

    // 1. new_queue = queue (D2D copy), k rows scattered later
    hipMemcpyAsync(out + 1, queue, (size_t)Q * M * sizeof(float),
                   hipMemcpyDeviceToDevice, stream);

    // 2-3. encoder GEMMs
    gemm_f32<<<dim3(H / TS, B / TS), 256, 0, stream>>>(y2, Wq, T1, B, H, D);
    gemm_f32<<<dim3(H / TS, B / TS), 256, 0, stream>>>(y1, Wk, T2, B, H, D);
    // 4-5. projection GEMMs
    gemm_f32<<<dim3(M / TS, B / TS), 256, 0, stream>>>(T1, Wp, qbuf, B, M, H);
    gemm_f32<<<dim3(M / TS, B / TS), 256, 0, stream>>>(T2, Wp, kbuf, B, M, H);
    // 6. normalize q and k in one launch (contiguous)
    row_l2norm<<<2 * B, 256, 0, stream>>>(qbuf, M);
    // 7. gather + normalize negatives
    gather_norm<<<NNEG, 256, 0, stream>>>(queue, sidx, negbuf, M);
    // 8. positive logits + sum-exp init
    pos_init<<<B, 256, 0, stream>>>(qbuf, kbuf, pos, sumexp, M, invT);
    // 9. fused negative logits + exp + row-sum
    logits_sumexp<<<dim3(NNEG / TS, B / TS), 256, 0, stream>>>(qbuf, negbuf, sumexp,
                                                               B, NNEG, M, invT);
    // 10. scatter k into new_queue
    scatter_k<<<B, 256, 0, stream>>>(kbuf, widx, out + 1, M);
    // 11. loss
    final_loss<<<1, 256, 0, stream>>>(pos, sumexp, out, B);
}

// Round 2
// 306.932 us; speedup vs baseline: 5.1692x; 5.1692x over previous
//
#include <hip/hip_runtime.h>
#include <hip/hip_bf16.h>
#include <math.h>
#include <stdint.h>

// ---------------------------------------------------------------------------
// MoCo contrastive: loss + queue update.  B=1024 D=2048 H=1024 M=256 Q=65536
// NNEG=16384, T=0.07.
// Round 2: all GEMMs -> bf16 MFMA (16x16x32), m97-style 128x128 tile,
// global_load_lds width-16 staging, split-K via fp32 atomics for occupancy.
// Weights pre-cast TRANSPOSED to bf16 so every GEMM is NT (both K-major).
// Logits GEMM fuses exp + row-sum (|logit| <= 1/T, single-pass is safe).
// ---------------------------------------------------------------------------

typedef __attribute__((ext_vector_type(4))) float floatx4;
typedef __attribute__((ext_vector_type(8))) short bf16x8;   // 8 bf16 = 4 VGPRs
typedef __attribute__((ext_vector_type(8))) unsigned short ushort8;

#define BM 128
#define BN 128
#define BK 32

__device__ __forceinline__ unsigned short f2bf(float x) {
    union { float f; unsigned int u; } v; v.f = x;
    unsigned int r = v.u + 0x7FFFu + ((v.u >> 16) & 1u);
    return (unsigned short)(r >> 16);
}

__device__ __forceinline__ void async_cp16(const void* g, void* l) {
    auto gp = reinterpret_cast<const __attribute__((address_space(1))) unsigned int*>(
        reinterpret_cast<uintptr_t>(g));
    auto lp = reinterpret_cast<__attribute__((address_space(3))) unsigned int*>(
        reinterpret_cast<uintptr_t>(l));
    __builtin_amdgcn_global_load_lds(gp, lp, 16, 0, 0);
}

// flat fp32 -> bf16 cast, 8 elements/thread, n % 2048 == 0
__global__ __launch_bounds__(256) void cast_bf16(const float* __restrict__ in,
                                                 unsigned short* __restrict__ out,
                                                 long n) {
    long i = (long)blockIdx.x * 256 + threadIdx.x;
    const float4* in4 = (const float4*)in;
    float4 a = in4[i * 2], b = in4[i * 2 + 1];
    ushort8 o;
    o[0] = f2bf(a.x); o[1] = f2bf(a.y); o[2] = f2bf(a.z); o[3] = f2bf(a.w);
    o[4] = f2bf(b.x); o[5] = f2bf(b.y); o[6] = f2bf(b.z); o[7] = f2bf(b.w);
    ((ushort8*)out)[i] = o;
}

// fp32 [R][C] -> bf16 [C][R]  (32x32 LDS tile)
__global__ __launch_bounds__(256) void transpose_cast(const float* __restrict__ in,
                                                      unsigned short* __restrict__ out,
                                                      int R, int C) {
    __shared__ unsigned short tile[32][33];
    int c0 = blockIdx.x * 32, r0 = blockIdx.y * 32;
    int tx = threadIdx.x & 31, ty = threadIdx.x >> 5;
#pragma unroll
    for (int i = 0; i < 4; ++i)
        tile[ty + i * 8][tx] = f2bf(in[(size_t)(r0 + ty + i * 8) * C + c0 + tx]);
    __syncthreads();
#pragma unroll
    for (int i = 0; i < 4; ++i)
        out[(size_t)(c0 + ty + i * 8) * R + r0 + tx] = tile[tx][ty + i * 8];
}

// ---------------------------------------------------------------------------
// NT MFMA GEMM: A [M][K] bf16, B [N][K] bf16 (both K-major), C [M][N] fp32.
// 128x128 block tile, 4 waves each 64x64 (4x4 of 16x16x32 MFMA). BK=32.
// Batched via z = batch*nsplit + split; split-K accumulates with atomicAdd
// (C must be pre-zeroed). All dims assumed divisible (they are here).
// ---------------------------------------------------------------------------
__global__ __launch_bounds__(256) void gemm_nt(const unsigned short* __restrict__ Ag,
                                               const unsigned short* __restrict__ Bg,
                                               float* __restrict__ Cg,
                                               int M_, int N_, int K_, int nsplit,
                                               long sAb, long sBb, long sCb) {
    __shared__ unsigned short As[BM * BK];
    __shared__ unsigned short Bs[BN * BK];
    const int z = blockIdx.z;
    const int batch = z / nsplit, split = z - batch * nsplit;
    const unsigned short* A = Ag + (long)batch * sAb;
    const unsigned short* B = Bg + (long)batch * sBb;
    float* C = Cg + (long)batch * sCb;
    const int Kc = K_ / nsplit;
    const int kbeg = split * Kc;
    const int row0 = blockIdx.y * BM, col0 = blockIdx.x * BN;
    const int t = threadIdx.x;
    const int wave = t >> 6, lane = t & 63;
    const int wr = wave >> 1, wc = wave & 1;
    const int lrow = lane & 15, quad = lane >> 4;

    floatx4 acc[4][4] = {};

    for (int kk = kbeg; kk < kbeg + Kc; kk += BK) {
#pragma unroll
        for (int r = 0; r < 2; ++r) {
            int c = t + r * 256;                   // 16B chunk id, 0..511
            int arow = c >> 2, aoff = (c & 3) * 8; // 4 chunks per 32-elem row
            async_cp16(A + (size_t)(row0 + arow) * K_ + kk + aoff,
                       (char*)As + (size_t)c * 16);
            async_cp16(B + (size_t)(col0 + arow) * K_ + kk + aoff,
                       (char*)Bs + (size_t)c * 16);
        }
        __syncthreads();   // drains vmcnt -> LDS tiles visible
        bf16x8 af[4], bfr[4];
#pragma unroll
        for (int i = 0; i < 4; ++i) {
            af[i]  = *(const bf16x8*)(As + (size_t)(wr * 64 + i * 16 + lrow) * BK + quad * 8);
            bfr[i] = *(const bf16x8*)(Bs + (size_t)(wc * 64 + i * 16 + lrow) * BK + quad * 8);
        }
#pragma unroll
        for (int i = 0; i < 4; ++i)
#pragma unroll
            for (int j = 0; j < 4; ++j)
                acc[i][j] = __builtin_amdgcn_mfma_f32_16x16x32_bf16(af[i], bfr[j], acc[i][j], 0, 0, 0);
        __syncthreads();
    }
    // C/D layout: col = lane&15, row = quad*4 + reg
#pragma unroll
    for (int i = 0; i < 4; ++i) {
        int grow = row0 + wr * 64 + i * 16 + quad * 4;
#pragma unroll
        for (int j = 0; j < 4; ++j) {
            int gcol = col0 + wc * 64 + j * 16 + lrow;
#pragma unroll
            for (int r = 0; r < 4; ++r)
                atomicAdd(&C[(size_t)(grow + r) * N_ + gcol], acc[i][j][r]);
        }
    }
}

// ---------------------------------------------------------------------------
// Fused logits GEMM: q [B][K] bf16, neg [NNEG][K] bf16 (NT), epilogue
// exp(acc/T) -> per-row sum -> atomicAdd into sumexp[B]. No split-K.
// ---------------------------------------------------------------------------
__global__ __launch_bounds__(256) void gemm_logits(const unsigned short* __restrict__ A,
                                                   const unsigned short* __restrict__ B,
                                                   float* __restrict__ sumexp,
                                                   int N_, int K_, float invT) {
    __shared__ unsigned short As[BM * BK];
    __shared__ unsigned short Bs[BN * BK];
    __shared__ float rowred[BM];
    const int row0 = blockIdx.y * BM, col0 = blockIdx.x * BN;
    const int t = threadIdx.x;
    const int wave = t >> 6, lane = t & 63;
    const int wr = wave >> 1, wc = wave & 1;
    const int lrow = lane & 15, quad = lane >> 4;

    floatx4 acc[4][4] = {};

    for (int kk = 0; kk < K_; kk += BK) {
#pragma unroll
        for (int r = 0; r < 2; ++r) {
            int c = t + r * 256;
            int arow = c >> 2, aoff = (c & 3) * 8;
            async_cp16(A + (size_t)(row0 + arow) * K_ + kk + aoff,
                       (char*)As + (size_t)c * 16);
            async_cp16(B + (size_t)(col0 + arow) * K_ + kk + aoff,
                       (char*)Bs + (size_t)c * 16);
        }
        __syncthreads();
        bf16x8 af[4], bfr[4];
#pragma unroll
        for (int i = 0; i < 4; ++i) {
            af[i]  = *(const bf16x8*)(As + (size_t)(wr * 64 + i * 16 + lrow) * BK + quad * 8);
            bfr[i] = *(const bf16x8*)(Bs + (size_t)(wc * 64 + i * 16 + lrow) * BK + quad * 8);
        }
#pragma unroll
        for (int i = 0; i < 4; ++i)
#pragma unroll
            for (int j = 0; j < 4; ++j)
                acc[i][j] = __builtin_amdgcn_mfma_f32_16x16x32_bf16(af[i], bfr[j], acc[i][j], 0, 0, 0);
        __syncthreads();
    }
    if (t < BM) rowred[t] = 0.f;
    __syncthreads();
#pragma unroll
    for (int i = 0; i < 4; ++i) {
#pragma unroll
        for (int r = 0; r < 4; ++r) {
            float s = 0.f;
#pragma unroll
            for (int j = 0; j < 4; ++j) s += __expf(acc[i][j][r] * invT);
            s += __shfl_xor(s, 1); s += __shfl_xor(s, 2);
            s += __shfl_xor(s, 4); s += __shfl_xor(s, 8);
            if (lrow == 0) atomicAdd(&rowred[wr * 64 + i * 16 + quad * 4 + r], s);
        }
    }
    __syncthreads();
    if (t < BM) atomicAdd(&sumexp[row0 + t], rowred[t]);
}

// in-place row l2norm over fp32 [nrows][256] + bf16 copy out
__global__ __launch_bounds__(256) void row_l2norm(float* __restrict__ X,
                                                  unsigned short* __restrict__ Xb) {
    const int r = blockIdx.x, t = threadIdx.x;
    float v = X[(size_t)r * 256 + t];
    __shared__ float s[256];
    s[t] = v * v;
    __syncthreads();
    for (int off = 128; off > 0; off >>= 1) {
        if (t < off) s[t] += s[t + off];
        __syncthreads();
    }
    float n = fmaxf(sqrtf(s[0]), 1e-12f);
    float o = v / n;
    X[(size_t)r * 256 + t] = o;
    Xb[(size_t)r * 256 + t] = f2bf(o);
}

// neg[j] = bf16(l2norm(queue[sidx[j]]))
__global__ __launch_bounds__(256) void gather_norm(const float* __restrict__ queue,
                                                   const int* __restrict__ sidx,
                                                   unsigned short* __restrict__ neg) {
    const int r = blockIdx.x, t = threadIdx.x;
    float v = queue[(size_t)sidx[r] * 256 + t];
    __shared__ float s[256];
    s[t] = v * v;
    __syncthreads();
    for (int off = 128; off > 0; off >>= 1) {
        if (t < off) s[t] += s[t + off];
        __syncthreads();
    }
    float n = fmaxf(sqrtf(s[0]), 1e-12f);
    neg[(size_t)r * 256 + t] = f2bf(v / n);
}

// pos[i] = dot(q_i,k_i)/T ; sumexp[i] = exp(pos[i])
__global__ __launch_bounds__(256) void pos_init(const float* __restrict__ q,
                                                const float* __restrict__ k,
                                                float* __restrict__ pos,
                                                float* __restrict__ sumexp, float invT) {
    const int r = blockIdx.x, t = threadIdx.x;
    float v = q[(size_t)r * 256 + t] * k[(size_t)r * 256 + t];
    __shared__ float s[256];
    s[t] = v;
    __syncthreads();
    for (int off = 128; off > 0; off >>= 1) {
        if (t < off) s[t] += s[t + off];
        __syncthreads();
    }
    if (t == 0) {
        float p = s[0] * invT;
        pos[r] = p;
        sumexp[r] = __expf(p);
    }
}

__global__ __launch_bounds__(256) void scatter_k(const float* __restrict__ k,
                                                 const int* __restrict__ widx,
                                                 float* __restrict__ newq) {
    const int r = blockIdx.x, t = threadIdx.x;
    newq[(size_t)widx[r] * 256 + t] = k[(size_t)r * 256 + t];
}

__global__ __launch_bounds__(256) void final_loss(const float* __restrict__ pos,
                                                  const float* __restrict__ sumexp,
                                                  float* __restrict__ out, int B_) {
    const int t = threadIdx.x;
    float acc = 0.f;
    for (int i = t; i < B_; i += 256) acc += logf(sumexp[i]) - pos[i];
    __shared__ float s[256];
    s[t] = acc;
    __syncthreads();
    for (int off = 128; off > 0; off >>= 1) {
        if (t < off) s[t] += s[t + off];
        __syncthreads();
    }
    if (t == 0) out[0] = s[0] / (float)B_;
}

extern "C" void kernel_launch(void* const* d_in, const int* in_sizes, int n_in,
                              void* d_out, int out_size, void* d_ws, size_t ws_size,
                              hipStream_t stream) {
    const float* y1    = (const float*)d_in[0];
    const float* y2    = (const float*)d_in[1];
    const float* Wq    = (const float*)d_in[2];
    const float* Wk    = (const float*)d_in[3];
    const float* Wp    = (const float*)d_in[4];
    const float* queue = (const float*)d_in[5];
    const int*   sidx  = (const int*)d_in[6];
    const int*   widx  = (const int*)d_in[7];
    float* out = (float*)d_out;

    const int B    = in_sizes[7];              // 1024
    const int NNEG = in_sizes[6];              // 16384
    const int D    = in_sizes[0] / B;          // 2048
    const int H    = in_sizes[2] / D;          // 1024
    const int M    = in_sizes[4] / H;          // 256
    const int Q    = in_sizes[5] / M;          // 65536
    const float invT = 1.0f / 0.07f;

    // ---- workspace layout ----
    // fp32: T1,T2 [B*H each] | qbuf,kbuf [B*M each] | pos,sumexp [B each]
    float* ws = (float*)d_ws;
    float* T1     = ws;
    float* T2     = T1 + (size_t)B * H;
    float* qbuf   = T2 + (size_t)B * H;
    float* kbuf   = qbuf + (size_t)B * M;
    float* pos    = kbuf + (size_t)B * M;
    float* sumexp = pos + B;
    // bf16 region (ushort), reusing dead buffers across phases:
    unsigned short* bs = (unsigned short*)(sumexp + B);
    unsigned short* y2b  = bs;                        // B*D  -> later T1b,T2b
    unsigned short* y1b  = bs + (size_t)B * D;        // B*D  -> later qkb
    unsigned short* Wqt  = y1b + (size_t)B * D;       // H*D  -> later negb
    unsigned short* Wkt  = Wqt + (size_t)H * D;       // H*D  -> (negb cont.)
    unsigned short* Wpt  = Wkt + (size_t)H * D;       // M*H
    unsigned short* T1b  = y2b;                       // B*H (alias, y2b dead)
    unsigned short* T2b  = y2b + (size_t)B * H;       // B*H (alias)
    unsigned short* qkb  = y1b;                       // 2*B*M (alias, y1b dead)
    unsigned short* negb = Wqt;                       // NNEG*M (alias, Wqt/Wkt dead)

    // 1. new_queue = queue (k rows scattered later)
    hipMemcpyAsync(out + 1, queue, (size_t)Q * M * sizeof(float),
                   hipMemcpyDeviceToDevice, stream);

    // 2. casts: activations flat, weights transposed
    cast_bf16<<<(int)((size_t)B * D / 2048), 256, 0, stream>>>(y2, y2b, (long)B * D);
    cast_bf16<<<(int)((size_t)B * D / 2048), 256, 0, stream>>>(y1, y1b, (long)B * D);
    transpose_cast<<<dim3(H / 32, D / 32), 256, 0, stream>>>(Wq, Wqt, D, H);
    transpose_cast<<<dim3(H / 32, D / 32), 256, 0, stream>>>(Wk, Wkt, D, H);
    transpose_cast<<<dim3(M / 32, H / 32), 256, 0, stream>>>(Wp, Wpt, H, M);

    // 3. encoder GEMMs: [B x H] = y@W, batched (z: 2 batches x 4 splits)
    hipMemsetAsync(T1, 0, (size_t)2 * B * H * sizeof(float), stream);
    gemm_nt<<<dim3(H / BN, B / BM, 8), 256, 0, stream>>>(
        y2b, Wqt, T1, B, H, D, 4, (long)B * D, (long)H * D, (long)B * H);

    // 4. cast T1,T2 -> bf16 (into y2b region)
    cast_bf16<<<(int)((size_t)2 * B * H / 2048), 256, 0, stream>>>(T1, T1b, (long)2 * B * H);

    // 5. gather + normalize negatives -> bf16 (into Wqt/Wkt region)
    gather_norm<<<NNEG, 256, 0, stream>>>(queue, sidx, negb);

    // 6. projection GEMMs: [B x M] = T@Wp, batched (z: 2 batches x 8 splits)
    hipMemsetAsync(qbuf, 0, (size_t)2 * B * M * sizeof(float), stream);
    gemm_nt<<<dim3(M / BN, B / BM, 16), 256, 0, stream>>>(
        T1b, Wpt, qbuf, B, M, H, 8, (long)B * H, 0L, (long)B * M);

    // 7. l2norm q,k (fp32 in place) + bf16 copy (into y1b region)
    row_l2norm<<<2 * B, 256, 0, stream>>>(qbuf, qkb);

    // 8. positive logits + sumexp init
    pos_init<<<B, 256, 0, stream>>>(qbuf, kbuf, pos, sumexp, invT);

    // 9. fused negative logits + exp + row-sum
    gemm_logits<<<dim3(NNEG / BN, B / BM, 1), 256, 0, stream>>>(
        qkb, negb, sumexp, NNEG, M, invT);

    // 10. scatter k rows into new_queue
    scatter_k<<<B, 256, 0, stream>>>(kbuf, widx, out + 1);

    // 11. loss
    final_loss<<<1, 256, 0, stream>>>(pos, sumexp, out, B);
}

// Round 3
// 256.678 us; speedup vs baseline: 6.1813x; 1.1958x over previous
//
#include <hip/hip_runtime.h>
#include <hip/hip_bf16.h>
#include <math.h>
#include <stdint.h>

// ---------------------------------------------------------------------------
// MoCo contrastive: loss + queue update.  B=1024 D=2048 H=1024 M=256 Q=65536
// NNEG=16384, T=0.07.
// Round 3: custom float4 queue-copy (rocclr copyBuffer was 1.9 TB/s);
// split-K GEMMs now atomic-free (per-split partial buffers + fused reduce);
// proj reduce fused with l2norm+cast+pos+scatter (qk_finalize);
// gather_norm = wave-per-row float4 + shfl.
// ---------------------------------------------------------------------------

typedef __attribute__((ext_vector_type(4))) float floatx4;
typedef __attribute__((ext_vector_type(8))) short bf16x8;   // 8 bf16 = 4 VGPRs
typedef __attribute__((ext_vector_type(8))) unsigned short ushort8;

#define BM 128
#define BN 128
#define BK 32

__device__ __forceinline__ unsigned short f2bf(float x) {
    union { float f; unsigned int u; } v; v.f = x;
    unsigned int r = v.u + 0x7FFFu + ((v.u >> 16) & 1u);
    return (unsigned short)(r >> 16);
}

__device__ __forceinline__ void async_cp16(const void* g, void* l) {
    auto gp = reinterpret_cast<const __attribute__((address_space(1))) unsigned int*>(
        reinterpret_cast<uintptr_t>(g));
    auto lp = reinterpret_cast<__attribute__((address_space(3))) unsigned int*>(
        reinterpret_cast<uintptr_t>(l));
    __builtin_amdgcn_global_load_lds(gp, lp, 16, 0, 0);
}

// grid-stride float4 copy (queue -> new_queue)
__global__ __launch_bounds__(256) void copy_f4(const float4* __restrict__ in,
                                               float4* __restrict__ out, int n4) {
    int i = blockIdx.x * 256 + threadIdx.x;
    int stride = gridDim.x * 256;
    for (; i < n4; i += stride) out[i] = in[i];
}

// flat fp32 -> bf16 cast, 8 elements/thread, n % 2048 == 0
__global__ __launch_bounds__(256) void cast_bf16(const float* __restrict__ in,
                                                 unsigned short* __restrict__ out,
                                                 long n) {
    long i = (long)blockIdx.x * 256 + threadIdx.x;
    const float4* in4 = (const float4*)in;
    float4 a = in4[i * 2], b = in4[i * 2 + 1];
    ushort8 o;
    o[0] = f2bf(a.x); o[1] = f2bf(a.y); o[2] = f2bf(a.z); o[3] = f2bf(a.w);
    o[4] = f2bf(b.x); o[5] = f2bf(b.y); o[6] = f2bf(b.z); o[7] = f2bf(b.w);
    ((ushort8*)out)[i] = o;
}

// fp32 [R][C] -> bf16 [C][R]  (32x32 LDS tile)
__global__ __launch_bounds__(256) void transpose_cast(const float* __restrict__ in,
                                                      unsigned short* __restrict__ out,
                                                      int R, int C) {
    __shared__ unsigned short tile[32][33];
    int c0 = blockIdx.x * 32, r0 = blockIdx.y * 32;
    int tx = threadIdx.x & 31, ty = threadIdx.x >> 5;
#pragma unroll
    for (int i = 0; i < 4; ++i)
        tile[ty + i * 8][tx] = f2bf(in[(size_t)(r0 + ty + i * 8) * C + c0 + tx]);
    __syncthreads();
#pragma unroll
    for (int i = 0; i < 4; ++i)
        out[(size_t)(c0 + ty + i * 8) * R + r0 + tx] = tile[tx][ty + i * 8];
}

// ---------------------------------------------------------------------------
// NT MFMA GEMM: A [M][K] bf16, B [N][K] bf16 (both K-major), C fp32 partials.
// z = batch*nsplit + split; each z writes its own M_*N_ partial (plain store).
// ---------------------------------------------------------------------------
__global__ __launch_bounds__(256) void gemm_nt(const unsigned short* __restrict__ Ag,
                                               const unsigned short* __restrict__ Bg,
                                               float* __restrict__ Cg,
                                               int M_, int N_, int K_, int nsplit,
                                               long sAb, long sBb) {
    __shared__ unsigned short As[BM * BK];
    __shared__ unsigned short Bs[BN * BK];
    const int z = blockIdx.z;
    const int batch = z / nsplit, split = z - batch * nsplit;
    const unsigned short* A = Ag + (long)batch * sAb;
    const unsigned short* B = Bg + (long)batch * sBb;
    float* C = Cg + (long)z * M_ * N_;
    const int Kc = K_ / nsplit;
    const int kbeg = split * Kc;
    const int row0 = blockIdx.y * BM, col0 = blockIdx.x * BN;
    const int t = threadIdx.x;
    const int wave = t >> 6, lane = t & 63;
    const int wr = wave >> 1, wc = wave & 1;
    const int lrow = lane & 15, quad = lane >> 4;

    floatx4 acc[4][4] = {};

    for (int kk = kbeg; kk < kbeg + Kc; kk += BK) {
#pragma unroll
        for (int r = 0; r < 2; ++r) {
            int c = t + r * 256;                   // 16B chunk id, 0..511
            int arow = c >> 2, aoff = (c & 3) * 8;
            async_cp16(A + (size_t)(row0 + arow) * K_ + kk + aoff,
                       (char*)As + (size_t)c * 16);
            async_cp16(B + (size_t)(col0 + arow) * K_ + kk + aoff,
                       (char*)Bs + (size_t)c * 16);
        }
        __syncthreads();
        bf16x8 af[4], bfr[4];
#pragma unroll
        for (int i = 0; i < 4; ++i) {
            af[i]  = *(const bf16x8*)(As + (size_t)(wr * 64 + i * 16 + lrow) * BK + quad * 8);
            bfr[i] = *(const bf16x8*)(Bs + (size_t)(wc * 64 + i * 16 + lrow) * BK + quad * 8);
        }
#pragma unroll
        for (int i = 0; i < 4; ++i)
#pragma unroll
            for (int j = 0; j < 4; ++j)
                acc[i][j] = __builtin_amdgcn_mfma_f32_16x16x32_bf16(af[i], bfr[j], acc[i][j], 0, 0, 0);
        __syncthreads();
    }
    // C/D layout: col = lane&15, row = quad*4 + reg
#pragma unroll
    for (int i = 0; i < 4; ++i) {
        int grow = row0 + wr * 64 + i * 16 + quad * 4;
#pragma unroll
        for (int j = 0; j < 4; ++j) {
            int gcol = col0 + wc * 64 + j * 16 + lrow;
#pragma unroll
            for (int r = 0; r < 4; ++r)
                C[(size_t)(grow + r) * N_ + gcol] = acc[i][j][r];
        }
    }
}

// encoder partial reduce (nsplit=2) + bf16 cast. 8 elems/thread.
// P layout: [batch][split][BH]; out: [batch][BH] bf16.
__global__ __launch_bounds__(256) void reduce2_cast(const float* __restrict__ P,
                                                    unsigned short* __restrict__ out,
                                                    long BH) {
    long i = ((long)blockIdx.x * 256 + threadIdx.x) * 8;
    long batch = (i >= BH) ? 1 : 0;
    long j = i - batch * BH;
    const float* p0 = P + batch * 2 * BH + j;
    const float* p1 = p0 + BH;
    float4 a0 = *(const float4*)p0, a1 = *(const float4*)(p0 + 4);
    float4 b0 = *(const float4*)p1, b1 = *(const float4*)(p1 + 4);
    ushort8 o;
    o[0] = f2bf(a0.x + b0.x); o[1] = f2bf(a0.y + b0.y);
    o[2] = f2bf(a0.z + b0.z); o[3] = f2bf(a0.w + b0.w);
    o[4] = f2bf(a1.x + b1.x); o[5] = f2bf(a1.y + b1.y);
    o[6] = f2bf(a1.z + b1.z); o[7] = f2bf(a1.w + b1.w);
    *(ushort8*)(out + i) = o;
}

// proj partial reduce (nsplit per batch) + l2norm + bf16 cast + pos/sumexp +
// scatter of normalized k rows into new_queue. One block per row pair i.
// P layout: [2*nsplit][B][256]  (q splits 0..ns-1, k splits ns..2ns-1)
__global__ __launch_bounds__(256) void qk_finalize(const float* __restrict__ P,
                                                   const int* __restrict__ widx,
                                                   unsigned short* __restrict__ qkb,
                                                   float* __restrict__ newq,
                                                   float* __restrict__ pos,
                                                   float* __restrict__ sumexp,
                                                   int B_, int nsplit, float invT) {
    const int i = blockIdx.x, t = threadIdx.x;
    const long RM = (long)B_ * 256;
    float sq = 0.f, sk = 0.f;
    for (int s = 0; s < nsplit; ++s) {
        sq += P[(long)s * RM + (long)i * 256 + t];
        sk += P[(long)(nsplit + s) * RM + (long)i * 256 + t];
    }
    __shared__ float r0[256], r1[256], r2[256];
    r0[t] = sq * sq; r1[t] = sk * sk; r2[t] = sq * sk;
    __syncthreads();
    for (int off = 128; off > 0; off >>= 1) {
        if (t < off) { r0[t] += r0[t + off]; r1[t] += r1[t + off]; r2[t] += r2[t + off]; }
        __syncthreads();
    }
    float nq = fmaxf(sqrtf(r0[0]), 1e-12f);
    float nk = fmaxf(sqrtf(r1[0]), 1e-12f);
    float qn = sq / nq, kn = sk / nk;
    qkb[(size_t)i * 256 + t] = f2bf(qn);
    qkb[(size_t)(B_ + i) * 256 + t] = f2bf(kn);
    newq[(size_t)widx[i] * 256 + t] = kn;
    if (t == 0) {
        float p = (r2[0] / (nq * nk)) * invT;
        pos[i] = p;
        sumexp[i] = __expf(p);
    }
}

// neg[r] = bf16(l2norm(queue[sidx[r]])), wave-per-row, float4 + shfl
__global__ __launch_bounds__(256) void gather_norm(const float* __restrict__ queue,
                                                   const int* __restrict__ sidx,
                                                   unsigned short* __restrict__ neg) {
    const int r = blockIdx.x * 4 + (threadIdx.x >> 6);
    const int lane = threadIdx.x & 63;
    const float4* src = (const float4*)(queue + (size_t)sidx[r] * 256);
    float4 v = src[lane];
    float ss = v.x * v.x + v.y * v.y + v.z * v.z + v.w * v.w;
#pragma unroll
    for (int off = 1; off < 64; off <<= 1) ss += __shfl_xor(ss, off);
    float inv = 1.f / fmaxf(sqrtf(ss), 1e-12f);
    ushort8 dummy; (void)dummy;
    unsigned short o[4] = { f2bf(v.x * inv), f2bf(v.y * inv),
                            f2bf(v.z * inv), f2bf(v.w * inv) };
    *(unsigned long long*)(neg + (size_t)r * 256 + lane * 4) =
        *(unsigned long long*)o;
}

// ---------------------------------------------------------------------------
// Fused logits GEMM: q [B][K] bf16, neg [NNEG][K] bf16 (NT), epilogue
// exp(acc/T) -> per-row sum -> atomicAdd into sumexp[B].
// ---------------------------------------------------------------------------
__global__ __launch_bounds__(256) void gemm_logits(const unsigned short* __restrict__ A,
                                                   const unsigned short* __restrict__ B,
                                                   float* __restrict__ sumexp,
                                                   int N_, int K_, float invT) {
    __shared__ unsigned short As[BM * BK];
    __shared__ unsigned short Bs[BN * BK];
    __shared__ float rowred[BM];
    const int row0 = blockIdx.y * BM, col0 = blockIdx.x * BN;
    const int t = threadIdx.x;
    const int wave = t >> 6, lane = t & 63;
    const int wr = wave >> 1, wc = wave & 1;
    const int lrow = lane & 15, quad = lane >> 4;

    floatx4 acc[4][4] = {};

    for (int kk = 0; kk < K_; kk += BK) {
#pragma unroll
        for (int r = 0; r < 2; ++r) {
            int c = t + r * 256;
            int arow = c >> 2, aoff = (c & 3) * 8;
            async_cp16(A + (size_t)(row0 + arow) * K_ + kk + aoff,
                       (char*)As + (size_t)c * 16);
            async_cp16(B + (size_t)(col0 + arow) * K_ + kk + aoff,
                       (char*)Bs + (size_t)c * 16);
        }
        __syncthreads();
        bf16x8 af[4], bfr[4];
#pragma unroll
        for (int i = 0; i < 4; ++i) {
            af[i]  = *(const bf16x8*)(As + (size_t)(wr * 64 + i * 16 + lrow) * BK + quad * 8);
            bfr[i] = *(const bf16x8*)(Bs + (size_t)(wc * 64 + i * 16 + lrow) * BK + quad * 8);
        }
#pragma unroll
        for (int i = 0; i < 4; ++i)
#pragma unroll
            for (int j = 0; j < 4; ++j)
                acc[i][j] = __builtin_amdgcn_mfma_f32_16x16x32_bf16(af[i], bfr[j], acc[i][j], 0, 0, 0);
        __syncthreads();
    }
    if (t < BM) rowred[t] = 0.f;
    __syncthreads();
#pragma unroll
    for (int i = 0; i < 4; ++i) {
#pragma unroll
        for (int r = 0; r < 4; ++r) {
            float s = 0.f;
#pragma unroll
            for (int j = 0; j < 4; ++j) s += __expf(acc[i][j][r] * invT);
            s += __shfl_xor(s, 1); s += __shfl_xor(s, 2);
            s += __shfl_xor(s, 4); s += __shfl_xor(s, 8);
            if (lrow == 0) atomicAdd(&rowred[wr * 64 + i * 16 + quad * 4 + r], s);
        }
    }
    __syncthreads();
    if (t < BM) atomicAdd(&sumexp[row0 + t], rowred[t]);
}

__global__ __launch_bounds__(256) void final_loss(const float* __restrict__ pos,
                                                  const float* __restrict__ sumexp,
                                                  float* __restrict__ out, int B_) {
    const int t = threadIdx.x;
    float acc = 0.f;
    for (int i = t; i < B_; i += 256) acc += logf(sumexp[i]) - pos[i];
    __shared__ float s[256];
    s[t] = acc;
    __syncthreads();
    for (int off = 128; off > 0; off >>= 1) {
        if (t < off) s[t] += s[t + off];
        __syncthreads();
    }
    if (t == 0) out[0] = s[0] / (float)B_;
}

extern "C" void kernel_launch(void* const* d_in, const int* in_sizes, int n_in,
                              void* d_out, int out_size, void* d_ws, size_t ws_size,
                              hipStream_t stream) {
    const float* y1    = (const float*)d_in[0];
    const float* y2    = (const float*)d_in[1];
    const float* Wq    = (const float*)d_in[2];
    const float* Wk    = (const float*)d_in[3];
    const float* Wp    = (const float*)d_in[4];
    const float* queue = (const float*)d_in[5];
    const int*   sidx  = (const int*)d_in[6];
    const int*   widx  = (const int*)d_in[7];
    float* out = (float*)d_out;

    const int B    = in_sizes[7];              // 1024
    const int NNEG = in_sizes[6];              // 16384
    const int D    = in_sizes[0] / B;          // 2048
    const int H    = in_sizes[2] / D;          // 1024
    const int M    = in_sizes[4] / H;          // 256
    const int Q    = in_sizes[5] / M;          // 65536
    const float invT = 1.0f / 0.07f;
    const int NS_E = 2;                        // encoder split-K
    const int NS_P = 8;                        // projection split-K

    // ---- workspace layout ----
    // fp32 partials (encoder 4*B*H  ==  proj 16*B*M, aliased): 4.19M floats
    float* ws  = (float*)d_ws;
    float* Pe  = ws;                                 // [2*NS_E][B*H]
    float* Pp  = ws;                                 // [2*NS_P][B*M] (alias)
    float* pos    = Pe + (size_t)2 * NS_E * B * H;
    float* sumexp = pos + B;
    // bf16 region
    unsigned short* bs  = (unsigned short*)(sumexp + B);
    unsigned short* y2b = bs;                        // B*D
    unsigned short* y1b = y2b + (size_t)B * D;       // B*D
    unsigned short* Wqt = y1b + (size_t)B * D;       // H*D
    unsigned short* Wkt = Wqt + (size_t)H * D;       // H*D
    unsigned short* Wpt = Wkt + (size_t)H * D;       // M*H
    unsigned short* T1b = y2b;                       // 2*B*H (alias, y2b dead after enc gemm)
    unsigned short* qkb = y1b;                       // 2*B*M (alias, y1b dead)
    unsigned short* negb = Wqt;                      // NNEG*M (alias, Wqt/Wkt dead)

    // 1. new_queue = queue (k rows overwritten later by qk_finalize)
    copy_f4<<<4096, 256, 0, stream>>>((const float4*)queue, (float4*)(out + 1),
                                      (int)((size_t)Q * M / 4));

    // 2. casts: activations flat, weights transposed
    cast_bf16<<<(int)((size_t)B * D / 2048), 256, 0, stream>>>(y2, y2b, (long)B * D);
    cast_bf16<<<(int)((size_t)B * D / 2048), 256, 0, stream>>>(y1, y1b, (long)B * D);
    transpose_cast<<<dim3(H / 32, D / 32), 256, 0, stream>>>(Wq, Wqt, D, H);
    transpose_cast<<<dim3(H / 32, D / 32), 256, 0, stream>>>(Wk, Wkt, D, H);
    transpose_cast<<<dim3(M / 32, H / 32), 256, 0, stream>>>(Wp, Wpt, H, M);

    // 3. encoder GEMMs: z = 2 batches x 2 splits -> Pe partials
    gemm_nt<<<dim3(H / BN, B / BM, 2 * NS_E), 256, 0, stream>>>(
        y2b, Wqt, Pe, B, H, D, NS_E, (long)B * D, (long)H * D);

    // 4. reduce partials + cast -> T1b/T2b
    reduce2_cast<<<(int)((size_t)2 * B * H / 2048), 256, 0, stream>>>(
        Pe, T1b, (long)B * H);

    // 5. gather + normalize negatives -> bf16
    gather_norm<<<NNEG / 4, 256, 0, stream>>>(queue, sidx, negb);

    // 6. projection GEMMs: z = 2 batches x 8 splits -> Pp partials
    gemm_nt<<<dim3(M / BN, B / BM, 2 * NS_P), 256, 0, stream>>>(
        T1b, Wpt, Pp, B, M, H, NS_P, (long)B * H, 0L);

    // 7. fused: reduce proj partials + l2norm + cast + pos/sumexp + scatter k
    qk_finalize<<<B, 256, 0, stream>>>(Pp, widx, qkb, out + 1, pos, sumexp,
                                       B, NS_P, invT);

    // 8. fused negative logits + exp + row-sum
    gemm_logits<<<dim3(NNEG / BN, B / BM, 1), 256, 0, stream>>>(
        qkb, negb, sumexp, NNEG, M, invT);

    // 9. loss
    final_loss<<<1, 256, 0, stream>>>(pos, sumexp, out, B);
}

// Round 4
// 239.832 us; speedup vs baseline: 6.6155x; 1.0702x over previous
//
#include <hip/hip_runtime.h>
#include <hip/hip_bf16.h>
#include <math.h>
#include <stdint.h>

// ---------------------------------------------------------------------------
// MoCo contrastive: loss + queue update.  B=1024 D=2048 H=1024 M=256 Q=65536
// NNEG=16384, T=0.07.
// Round 4: single "prep" kernel (copy+casts+transposes+gather) replaces 7
// launches; encoder GEMM -> BM128/BN64 no-split with direct bf16 epilogue
// (kills reduce kernel + 32MB partials); logits GEMM BK=64 (32 MFMA/barrier).
// 6 dispatches total.
// ---------------------------------------------------------------------------

typedef __attribute__((ext_vector_type(4))) float floatx4;
typedef __attribute__((ext_vector_type(8))) short bf16x8;   // 8 bf16 = 4 VGPRs
typedef __attribute__((ext_vector_type(8))) unsigned short ushort8;

__device__ __forceinline__ unsigned short f2bf(float x) {
    union { float f; unsigned int u; } v; v.f = x;
    unsigned int r = v.u + 0x7FFFu + ((v.u >> 16) & 1u);
    return (unsigned short)(r >> 16);
}

__device__ __forceinline__ void async_cp16(const void* g, void* l) {
    auto gp = reinterpret_cast<const __attribute__((address_space(1))) unsigned int*>(
        reinterpret_cast<uintptr_t>(g));
    auto lp = reinterpret_cast<__attribute__((address_space(3))) unsigned int*>(
        reinterpret_cast<uintptr_t>(l));
    __builtin_amdgcn_global_load_lds(gp, lp, 16, 0, 0);
}

// ---------------------------------------------------------------------------
// prep: everything that depends only on inputs, one dispatch.
//   [0, nCopy)                queue -> new_queue (float4)
//   [nCopy, +1024)            cast y2 -> y2b
//   [.., +1024)               cast y1 -> y1b
//   [.., +2048)               transpose Wq [D][H] -> Wqt [H][D]
//   [.., +2048)               transpose Wk -> Wkt
//   [.., +256)                transpose Wp [H][M] -> Wpt [M][H]
//   [.., +NNEG/4)             gather+l2norm negatives -> negb
// ---------------------------------------------------------------------------
__global__ __launch_bounds__(256) void prep(
    const float4* __restrict__ queue4, float4* __restrict__ newq4, int nCopy,
    const float* __restrict__ y2, const float* __restrict__ y1,
    unsigned short* __restrict__ y2b, unsigned short* __restrict__ y1b,
    const float* __restrict__ Wq, const float* __restrict__ Wk,
    const float* __restrict__ Wp,
    unsigned short* __restrict__ Wqt, unsigned short* __restrict__ Wkt,
    unsigned short* __restrict__ Wpt,
    const float* __restrict__ queue, const int* __restrict__ sidx,
    unsigned short* __restrict__ negb,
    int D, int H, int M) {
    __shared__ unsigned short tile[32][33];
    const int b = blockIdx.x, t = threadIdx.x;
    const int nCastY = 1024;           // B*D/2048 with B=1024,D=2048
    const int nTW = (D / 32) * (H / 32);
    const int nTWp = (H / 32) * (M / 32);

    if (b < nCopy) {
        int base = b * 1024 + t;
#pragma unroll
        for (int i = 0; i < 4; ++i) newq4[base + i * 256] = queue4[base + i * 256];
        return;
    }
    int bb = b - nCopy;
    if (bb < 2 * nCastY) {             // bf16 casts, 8 elems/thread
        const float* in = (bb < nCastY) ? y2 : y1;
        unsigned short* outp = (bb < nCastY) ? y2b : y1b;
        long i = (long)(bb % nCastY) * 256 + t;
        const float4* in4 = (const float4*)in;
        float4 a = in4[i * 2], c = in4[i * 2 + 1];
        ushort8 o;
        o[0] = f2bf(a.x); o[1] = f2bf(a.y); o[2] = f2bf(a.z); o[3] = f2bf(a.w);
        o[4] = f2bf(c.x); o[5] = f2bf(c.y); o[6] = f2bf(c.z); o[7] = f2bf(c.w);
        ((ushort8*)outp)[i] = o;
        return;
    }
    bb -= 2 * nCastY;
    if (bb < 2 * nTW + nTWp) {         // transposes: in [R][C] -> out [C][R]
        const float* in; unsigned short* outp; int R, C, idx;
        if (bb < nTW)           { in = Wq; outp = Wqt; R = D; C = H; idx = bb; }
        else if (bb < 2 * nTW)  { in = Wk; outp = Wkt; R = D; C = H; idx = bb - nTW; }
        else                    { in = Wp; outp = Wpt; R = H; C = M; idx = bb - 2 * nTW; }
        int cb = C / 32;
        int c0 = (idx % cb) * 32, r0 = (idx / cb) * 32;
        int tx = t & 31, ty = t >> 5;
#pragma unroll
        for (int i = 0; i < 4; ++i)
            tile[ty + i * 8][tx] = f2bf(in[(size_t)(r0 + ty + i * 8) * C + c0 + tx]);
        __syncthreads();
#pragma unroll
        for (int i = 0; i < 4; ++i)
            outp[(size_t)(c0 + ty + i * 8) * R + r0 + tx] = tile[tx][ty + i * 8];
        return;
    }
    bb -= 2 * nTW + nTWp;
    {                                   // gather + l2norm, wave per row
        int r = bb * 4 + (t >> 6);
        int lane = t & 63;
        const float4* src = (const float4*)(queue + (size_t)sidx[r] * 256);
        float4 v = src[lane];
        float ss = v.x * v.x + v.y * v.y + v.z * v.z + v.w * v.w;
#pragma unroll
        for (int off = 1; off < 64; off <<= 1) ss += __shfl_xor(ss, off);
        float inv = 1.f / fmaxf(sqrtf(ss), 1e-12f);
        unsigned short o[4] = { f2bf(v.x * inv), f2bf(v.y * inv),
                                f2bf(v.z * inv), f2bf(v.w * inv) };
        *(unsigned long long*)(negb + (size_t)r * 256 + lane * 4) =
            *(unsigned long long*)o;
    }
}

// ---------------------------------------------------------------------------
// Encoder GEMM: A [1024][K] bf16, B [N][K] bf16 (NT), out bf16 [1024][N].
// BM=128 BN=64 BK=32, no split-K, direct bf16 epilogue. z = batch.
// ---------------------------------------------------------------------------
__global__ __launch_bounds__(256) void gemm_enc(const unsigned short* __restrict__ Ag,
                                                const unsigned short* __restrict__ Bg,
                                                unsigned short* __restrict__ Cg,
                                                int No, int Ko,
                                                long sAb, long sBb, long sCb) {
    __shared__ unsigned short As[128 * 32];
    __shared__ unsigned short Bs[64 * 32];
    const int batch = blockIdx.z;
    const unsigned short* A = Ag + (long)batch * sAb;
    const unsigned short* B = Bg + (long)batch * sBb;
    unsigned short* C = Cg + (long)batch * sCb;
    const int row0 = blockIdx.y * 128, col0 = blockIdx.x * 64;
    const int t = threadIdx.x;
    const int lane = t & 63, wave = t >> 6;
    const int wr = wave >> 1, wc = wave & 1;
    const int lrow = lane & 15, quad = lane >> 4;

    floatx4 acc[4][2] = {};

    for (int kk = 0; kk < Ko; kk += 32) {
        {   // As: 512 chunks (2/thread), Bs: 256 chunks (1/thread)
            int c0 = t, c1 = t + 256;
            async_cp16(A + (size_t)(row0 + (c0 >> 2)) * Ko + kk + (c0 & 3) * 8,
                       (char*)As + (size_t)c0 * 16);
            async_cp16(A + (size_t)(row0 + (c1 >> 2)) * Ko + kk + (c1 & 3) * 8,
                       (char*)As + (size_t)c1 * 16);
            async_cp16(B + (size_t)(col0 + (t >> 2)) * Ko + kk + (t & 3) * 8,
                       (char*)Bs + (size_t)t * 16);
        }
        __syncthreads();
        bf16x8 af[4], bf[2];
#pragma unroll
        for (int i = 0; i < 4; ++i)
            af[i] = *(const bf16x8*)(As + (size_t)(wr * 64 + i * 16 + lrow) * 32 + quad * 8);
#pragma unroll
        for (int j = 0; j < 2; ++j)
            bf[j] = *(const bf16x8*)(Bs + (size_t)(wc * 32 + j * 16 + lrow) * 32 + quad * 8);
#pragma unroll
        for (int i = 0; i < 4; ++i)
#pragma unroll
            for (int j = 0; j < 2; ++j)
                acc[i][j] = __builtin_amdgcn_mfma_f32_16x16x32_bf16(af[i], bf[j], acc[i][j], 0, 0, 0);
        __syncthreads();
    }
    // C/D: col = lrow, row = quad*4 + reg
#pragma unroll
    for (int i = 0; i < 4; ++i) {
        int grow = row0 + wr * 64 + i * 16 + quad * 4;
#pragma unroll
        for (int j = 0; j < 2; ++j) {
            int gcol = col0 + wc * 32 + j * 16 + lrow;
#pragma unroll
            for (int r = 0; r < 4; ++r)
                C[(size_t)(grow + r) * No + gcol] = f2bf(acc[i][j][r]);
        }
    }
}

// ---------------------------------------------------------------------------
// Projection GEMM: A [1024][1024] bf16, B=Wpt [256][1024] bf16 (NT), fp32
// partials. BM=128 BN=64 BK=32, z = batch*NS + split (NS=4).
// ---------------------------------------------------------------------------
__global__ __launch_bounds__(256) void gemm_proj(const unsigned short* __restrict__ Ag,
                                                 const unsigned short* __restrict__ Bg,
                                                 float* __restrict__ Pg,
                                                 int No, int Ko, int nsplit,
                                                 long sAb) {
    __shared__ unsigned short As[128 * 32];
    __shared__ unsigned short Bs[64 * 32];
    const int z = blockIdx.z;
    const int batch = z / nsplit, split = z - batch * nsplit;
    const unsigned short* A = Ag + (long)batch * sAb;
    const unsigned short* B = Bg;
    float* P = Pg + (long)z * 1024 * No;
    const int Kc = Ko / nsplit, kbeg = split * Kc;
    const int row0 = blockIdx.y * 128, col0 = blockIdx.x * 64;
    const int t = threadIdx.x;
    const int lane = t & 63, wave = t >> 6;
    const int wr = wave >> 1, wc = wave & 1;
    const int lrow = lane & 15, quad = lane >> 4;

    floatx4 acc[4][2] = {};

    for (int kk = kbeg; kk < kbeg + Kc; kk += 32) {
        {
            int c0 = t, c1 = t + 256;
            async_cp16(A + (size_t)(row0 + (c0 >> 2)) * Ko + kk + (c0 & 3) * 8,
                       (char*)As + (size_t)c0 * 16);
            async_cp16(A + (size_t)(row0 + (c1 >> 2)) * Ko + kk + (c1 & 3) * 8,
                       (char*)As + (size_t)c1 * 16);
            async_cp16(B + (size_t)(col0 + (t >> 2)) * Ko + kk + (t & 3) * 8,
                       (char*)Bs + (size_t)t * 16);
        }
        __syncthreads();
        bf16x8 af[4], bf[2];
#pragma unroll
        for (int i = 0; i < 4; ++i)
            af[i] = *(const bf16x8*)(As + (size_t)(wr * 64 + i * 16 + lrow) * 32 + quad * 8);
#pragma unroll
        for (int j = 0; j < 2; ++j)
            bf[j] = *(const bf16x8*)(Bs + (size_t)(wc * 32 + j * 16 + lrow) * 32 + quad * 8);
#pragma unroll
        for (int i = 0; i < 4; ++i)
#pragma unroll
            for (int j = 0; j < 2; ++j)
                acc[i][j] = __builtin_amdgcn_mfma_f32_16x16x32_bf16(af[i], bf[j], acc[i][j], 0, 0, 0);
        __syncthreads();
    }
#pragma unroll
    for (int i = 0; i < 4; ++i) {
        int grow = row0 + wr * 64 + i * 16 + quad * 4;
#pragma unroll
        for (int j = 0; j < 2; ++j) {
            int gcol = col0 + wc * 32 + j * 16 + lrow;
#pragma unroll
            for (int r = 0; r < 4; ++r)
                P[(size_t)(grow + r) * No + gcol] = acc[i][j][r];
        }
    }
}

// reduce proj partials + l2norm + bf16 cast + pos/sumexp + scatter k rows.
// P layout: [2*nsplit][B][256] (q: 0..ns-1, k: ns..2ns-1). One block/row.
__global__ __launch_bounds__(256) void qk_finalize(const float* __restrict__ P,
                                                   const int* __restrict__ widx,
                                                   unsigned short* __restrict__ qkb,
                                                   float* __restrict__ newq,
                                                   float* __restrict__ pos,
                                                   float* __restrict__ sumexp,
                                                   int B_, int nsplit, float invT) {
    const int i = blockIdx.x, t = threadIdx.x;
    const long RM = (long)B_ * 256;
    float sq = 0.f, sk = 0.f;
    for (int s = 0; s < nsplit; ++s) {
        sq += P[(long)s * RM + (long)i * 256 + t];
        sk += P[(long)(nsplit + s) * RM + (long)i * 256 + t];
    }
    __shared__ float r0[256], r1[256], r2[256];
    r0[t] = sq * sq; r1[t] = sk * sk; r2[t] = sq * sk;
    __syncthreads();
    for (int off = 128; off > 0; off >>= 1) {
        if (t < off) { r0[t] += r0[t + off]; r1[t] += r1[t + off]; r2[t] += r2[t + off]; }
        __syncthreads();
    }
    float nq = fmaxf(sqrtf(r0[0]), 1e-12f);
    float nk = fmaxf(sqrtf(r1[0]), 1e-12f);
    float qn = sq / nq, kn = sk / nk;
    qkb[(size_t)i * 256 + t] = f2bf(qn);
    qkb[(size_t)(B_ + i) * 256 + t] = f2bf(kn);
    newq[(size_t)widx[i] * 256 + t] = kn;
    if (t == 0) {
        float p = (r2[0] / (nq * nk)) * invT;
        pos[i] = p;
        sumexp[i] = __expf(p);
    }
}

// ---------------------------------------------------------------------------
// Fused logits GEMM: q [B][256] bf16, neg [NNEG][256] bf16 (NT), BK=64,
// epilogue exp(acc/T) -> row-sum -> atomicAdd sumexp.
// ---------------------------------------------------------------------------
__global__ __launch_bounds__(256) void gemm_logits(const unsigned short* __restrict__ A,
                                                   const unsigned short* __restrict__ B,
                                                   float* __restrict__ sumexp,
                                                   int Ko, float invT) {
    __shared__ unsigned short As[128 * 64];
    __shared__ unsigned short Bs[128 * 64];
    __shared__ float rowred[128];
    const int row0 = blockIdx.y * 128, col0 = blockIdx.x * 128;
    const int t = threadIdx.x;
    const int lane = t & 63, wave = t >> 6;
    const int wr = wave >> 1, wc = wave & 1;
    const int lrow = lane & 15, quad = lane >> 4;

    floatx4 acc[4][4] = {};

    for (int kk = 0; kk < Ko; kk += 64) {
#pragma unroll
        for (int r = 0; r < 4; ++r) {
            int c = t + r * 256;
            async_cp16(A + (size_t)(row0 + (c >> 3)) * Ko + kk + (c & 7) * 8,
                       (char*)As + (size_t)c * 16);
            async_cp16(B + (size_t)(col0 + (c >> 3)) * Ko + kk + (c & 7) * 8,
                       (char*)Bs + (size_t)c * 16);
        }
        __syncthreads();
        bf16x8 af[4][2], bf[4][2];
#pragma unroll
        for (int i = 0; i < 4; ++i)
#pragma unroll
            for (int k2 = 0; k2 < 2; ++k2) {
                af[i][k2] = *(const bf16x8*)(As + (size_t)(wr * 64 + i * 16 + lrow) * 64 + k2 * 32 + quad * 8);
                bf[i][k2] = *(const bf16x8*)(Bs + (size_t)(wc * 64 + i * 16 + lrow) * 64 + k2 * 32 + quad * 8);
            }
#pragma unroll
        for (int k2 = 0; k2 < 2; ++k2)
#pragma unroll
            for (int i = 0; i < 4; ++i)
#pragma unroll
                for (int j = 0; j < 4; ++j)
                    acc[i][j] = __builtin_amdgcn_mfma_f32_16x16x32_bf16(af[i][k2], bf[j][k2], acc[i][j], 0, 0, 0);
        __syncthreads();
    }
    if (t < 128) rowred[t] = 0.f;
    __syncthreads();
#pragma unroll
    for (int i = 0; i < 4; ++i) {
#pragma unroll
        for (int r = 0; r < 4; ++r) {
            float s = 0.f;
#pragma unroll
            for (int j = 0; j < 4; ++j) s += __expf(acc[i][j][r] * invT);
            s += __shfl_xor(s, 1); s += __shfl_xor(s, 2);
            s += __shfl_xor(s, 4); s += __shfl_xor(s, 8);
            if (lrow == 0) atomicAdd(&rowred[wr * 64 + i * 16 + quad * 4 + r], s);
        }
    }
    __syncthreads();
    if (t < 128) atomicAdd(&sumexp[row0 + t], rowred[t]);
}

__global__ __launch_bounds__(256) void final_loss(const float* __restrict__ pos,
                                                  const float* __restrict__ sumexp,
                                                  float* __restrict__ out, int B_) {
    const int t = threadIdx.x;
    float acc = 0.f;
    for (int i = t; i < B_; i += 256) acc += logf(sumexp[i]) - pos[i];
    __shared__ float s[256];
    s[t] = acc;
    __syncthreads();
    for (int off = 128; off > 0; off >>= 1) {
        if (t < off) s[t] += s[t + off];
        __syncthreads();
    }
    if (t == 0) out[0] = s[0] / (float)B_;
}

extern "C" void kernel_launch(void* const* d_in, const int* in_sizes, int n_in,
                              void* d_out, int out_size, void* d_ws, size_t ws_size,
                              hipStream_t stream) {
    const float* y1    = (const float*)d_in[0];
    const float* y2    = (const float*)d_in[1];
    const float* Wq    = (const float*)d_in[2];
    const float* Wk    = (const float*)d_in[3];
    const float* Wp    = (const float*)d_in[4];
    const float* queue = (const float*)d_in[5];
    const int*   sidx  = (const int*)d_in[6];
    const int*   widx  = (const int*)d_in[7];
    float* out = (float*)d_out;

    const int B    = in_sizes[7];              // 1024
    const int NNEG = in_sizes[6];              // 16384
    const int D    = in_sizes[0] / B;          // 2048
    const int H    = in_sizes[2] / D;          // 1024
    const int M    = in_sizes[4] / H;          // 256
    const int Q    = in_sizes[5] / M;          // 65536
    const float invT = 1.0f / 0.07f;
    const int NS_P = 4;

    // ---- workspace layout (no aliasing; ws is ~268MB) ----
    float* ws  = (float*)d_ws;
    float* Pp     = ws;                              // [2*NS_P][B*M] = 2M floats
    float* pos    = Pp + (size_t)2 * NS_P * B * M;
    float* sumexp = pos + B;
    unsigned short* us = (unsigned short*)(sumexp + B);
    unsigned short* y2b  = us;                       // B*D
    unsigned short* y1b  = y2b + (size_t)B * D;      // B*D
    unsigned short* Wqt  = y1b + (size_t)B * D;      // H*D
    unsigned short* Wkt  = Wqt + (size_t)H * D;      // H*D
    unsigned short* Wpt  = Wkt + (size_t)H * D;      // M*H
    unsigned short* T12b = Wpt + (size_t)M * H;      // 2*B*H
    unsigned short* qkb  = T12b + (size_t)2 * B * H; // 2*B*M
    unsigned short* negb = qkb + (size_t)2 * B * M;  // NNEG*M

    // 1. prep: copy + casts + transposes + gather (one dispatch)
    const int nCopy = (int)((size_t)Q * M / 4 / 1024);           // 4096
    const int nPrep = nCopy + 2 * 1024 + 2 * (D / 32) * (H / 32)
                    + (H / 32) * (M / 32) + NNEG / 4;
    prep<<<nPrep, 256, 0, stream>>>((const float4*)queue, (float4*)(out + 1), nCopy,
                                    y2, y1, y2b, y1b, Wq, Wk, Wp, Wqt, Wkt, Wpt,
                                    queue, sidx, negb, D, H, M);

    // 2. encoder GEMMs (both batches), direct bf16 out
    gemm_enc<<<dim3(H / 64, B / 128, 2), 256, 0, stream>>>(
        y2b, Wqt, T12b, H, D, (long)B * D, (long)H * D, (long)B * H);

    // 3. projection GEMMs -> fp32 partials (z = 2 batches x NS_P splits)
    gemm_proj<<<dim3(M / 64, B / 128, 2 * NS_P), 256, 0, stream>>>(
        T12b, Wpt, Pp, M, H, NS_P, (long)B * H);

    // 4. fused reduce + l2norm + cast + pos/sumexp + scatter k
    qk_finalize<<<B, 256, 0, stream>>>(Pp, widx, qkb, out + 1, pos, sumexp,
                                       B, NS_P, invT);

    // 5. fused negative logits + exp + row-sum
    gemm_logits<<<dim3(NNEG / 128, B / 128), 256, 0, stream>>>(
        qkb, negb, sumexp, M, invT);

    // 6. loss
    final_loss<<<1, 256, 0, stream>>>(pos, sumexp, out, B);
}

// Round 5
// 232.742 us; speedup vs baseline: 6.8170x; 1.0305x over previous
//
#include <hip/hip_runtime.h>
#include <hip/hip_bf16.h>
#include <math.h>
#include <stdint.h>

// ---------------------------------------------------------------------------
// MoCo contrastive: loss + queue update.  B=1024 D=2048 H=1024 M=256 Q=65536
// NNEG=16384, T=0.07.
// Round 5: heterogeneous-block "enc_plus" dispatch = encoder MFMA GEMM blocks
// interleaved (1:4:2 pattern) with queue-copy blocks (128MB) and gather+norm
// blocks -- memory work hides under MFMA latency on the same CUs (m114
// co-scheduling). prep shrinks to casts+transposes. 6 dispatches.
// ---------------------------------------------------------------------------

typedef __attribute__((ext_vector_type(4))) float floatx4;
typedef __attribute__((ext_vector_type(8))) short bf16x8;   // 8 bf16 = 4 VGPRs
typedef __attribute__((ext_vector_type(8))) unsigned short ushort8;

__device__ __forceinline__ unsigned short f2bf(float x) {
    union { float f; unsigned int u; } v; v.f = x;
    unsigned int r = v.u + 0x7FFFu + ((v.u >> 16) & 1u);
    return (unsigned short)(r >> 16);
}

__device__ __forceinline__ void async_cp16(const void* g, void* l) {
    auto gp = reinterpret_cast<const __attribute__((address_space(1))) unsigned int*>(
        reinterpret_cast<uintptr_t>(g));
    auto lp = reinterpret_cast<__attribute__((address_space(3))) unsigned int*>(
        reinterpret_cast<uintptr_t>(l));
    __builtin_amdgcn_global_load_lds(gp, lp, 16, 0, 0);
}

// ---------------------------------------------------------------------------
// prep_small: y casts + weight transposes (everything the enc GEMM needs).
//   [0,1024)  cast y2 -> y2b      [1024,2048) cast y1 -> y1b
//   [+2048)   transpose Wq        [+2048)     transpose Wk
//   [+256)    transpose Wp
// ---------------------------------------------------------------------------
__global__ __launch_bounds__(256) void prep_small(
    const float* __restrict__ y2, const float* __restrict__ y1,
    unsigned short* __restrict__ y2b, unsigned short* __restrict__ y1b,
    const float* __restrict__ Wq, const float* __restrict__ Wk,
    const float* __restrict__ Wp,
    unsigned short* __restrict__ Wqt, unsigned short* __restrict__ Wkt,
    unsigned short* __restrict__ Wpt,
    int D, int H, int M) {
    __shared__ unsigned short tile[32][33];
    const int b = blockIdx.x, t = threadIdx.x;
    const int nCastY = 1024;           // B*D/2048
    const int nTW = (D / 32) * (H / 32);

    if (b < 2 * nCastY) {              // bf16 casts, 8 elems/thread
        const float* in = (b < nCastY) ? y2 : y1;
        unsigned short* outp = (b < nCastY) ? y2b : y1b;
        long i = (long)(b % nCastY) * 256 + t;
        const float4* in4 = (const float4*)in;
        float4 a = in4[i * 2], c = in4[i * 2 + 1];
        ushort8 o;
        o[0] = f2bf(a.x); o[1] = f2bf(a.y); o[2] = f2bf(a.z); o[3] = f2bf(a.w);
        o[4] = f2bf(c.x); o[5] = f2bf(c.y); o[6] = f2bf(c.z); o[7] = f2bf(c.w);
        ((ushort8*)outp)[i] = o;
        return;
    }
    int bb = b - 2 * nCastY;           // transposes: in [R][C] -> out [C][R]
    const float* in; unsigned short* outp; int R, C, idx;
    if (bb < nTW)           { in = Wq; outp = Wqt; R = D; C = H; idx = bb; }
    else if (bb < 2 * nTW)  { in = Wk; outp = Wkt; R = D; C = H; idx = bb - nTW; }
    else                    { in = Wp; outp = Wpt; R = H; C = M; idx = bb - 2 * nTW; }
    int cb = C / 32;
    int c0 = (idx % cb) * 32, r0 = (idx / cb) * 32;
    int tx = t & 31, ty = t >> 5;
#pragma unroll
    for (int i = 0; i < 4; ++i)
        tile[ty + i * 8][tx] = f2bf(in[(size_t)(r0 + ty + i * 8) * C + c0 + tx]);
    __syncthreads();
#pragma unroll
    for (int i = 0; i < 4; ++i)
        outp[(size_t)(c0 + ty + i * 8) * R + r0 + tx] = tile[tx][ty + i * 8];
}

// ---------------------------------------------------------------------------
// enc_plus: 1792 blocks, b%7 pattern -> 256 GEMM : 1024 copy : 512 gather.
//  GEMM: A [1024][2048] bf16 x W^T [1024][2048] bf16 (NT), BM=128 BN=64 BK=32,
//        direct bf16 epilogue into T12b. z(batch) folded into block id.
//  copy: queue -> new_queue, 128KB/block float4.
//  gather: neg[r] = bf16(l2norm(queue[sidx[r]])), 32 rows/block.
// ---------------------------------------------------------------------------
__global__ __launch_bounds__(256) void enc_plus(
    const unsigned short* __restrict__ Yb,   // y2b | y1b  (stride B*D)
    const unsigned short* __restrict__ Wt,   // Wqt | Wkt  (stride H*D)
    unsigned short* __restrict__ T12b,       // [2][B][H] bf16
    const float4* __restrict__ queue4, float4* __restrict__ newq4,
    const float* __restrict__ queue, const int* __restrict__ sidx,
    unsigned short* __restrict__ negb) {
    __shared__ unsigned short As[128 * 32];
    __shared__ unsigned short Bs[64 * 32];
    const int b = blockIdx.x, t = threadIdx.x;
    const int type = b % 7, id = b / 7;

    if (type == 0) {
        // -------- encoder GEMM block, id in [0,256) --------
        const int batch = id >> 7, rem = id & 127;
        const int col0 = (rem & 15) * 64, row0 = (rem >> 4) * 128;
        const unsigned short* A = Yb + (long)batch * 1024 * 2048;
        const unsigned short* Bp = Wt + (long)batch * 1024 * 2048;
        unsigned short* C = T12b + (long)batch * 1024 * 1024;
        const int Ko = 2048, No = 1024;
        const int lane = t & 63, wave = t >> 6;
        const int wr = wave >> 1, wc = wave & 1;
        const int lrow = lane & 15, quad = lane >> 4;

        floatx4 acc[4][2] = {};
        for (int kk = 0; kk < Ko; kk += 32) {
            int c0 = t, c1 = t + 256;
            async_cp16(A + (size_t)(row0 + (c0 >> 2)) * Ko + kk + (c0 & 3) * 8,
                       (char*)As + (size_t)c0 * 16);
            async_cp16(A + (size_t)(row0 + (c1 >> 2)) * Ko + kk + (c1 & 3) * 8,
                       (char*)As + (size_t)c1 * 16);
            async_cp16(Bp + (size_t)(col0 + (t >> 2)) * Ko + kk + (t & 3) * 8,
                       (char*)Bs + (size_t)t * 16);
            __syncthreads();
            bf16x8 af[4], bf[2];
#pragma unroll
            for (int i = 0; i < 4; ++i)
                af[i] = *(const bf16x8*)(As + (size_t)(wr * 64 + i * 16 + lrow) * 32 + quad * 8);
#pragma unroll
            for (int j = 0; j < 2; ++j)
                bf[j] = *(const bf16x8*)(Bs + (size_t)(wc * 32 + j * 16 + lrow) * 32 + quad * 8);
#pragma unroll
            for (int i = 0; i < 4; ++i)
#pragma unroll
                for (int j = 0; j < 2; ++j)
                    acc[i][j] = __builtin_amdgcn_mfma_f32_16x16x32_bf16(af[i], bf[j], acc[i][j], 0, 0, 0);
            __syncthreads();
        }
#pragma unroll
        for (int i = 0; i < 4; ++i) {
            int grow = row0 + wr * 64 + i * 16 + quad * 4;
#pragma unroll
            for (int j = 0; j < 2; ++j) {
                int gcol = col0 + wc * 32 + j * 16 + lrow;
#pragma unroll
                for (int r = 0; r < 4; ++r)
                    C[(size_t)(grow + r) * No + gcol] = f2bf(acc[i][j][r]);
            }
        }
    } else if (type == 3 || type == 6) {
        // -------- gather+l2norm, gid in [0,512), 32 rows each --------
        const int gid = id * 2 + (type == 6);
        const int w = t >> 6, lane = t & 63;
#pragma unroll
        for (int j = 0; j < 8; ++j) {
            int r = gid * 32 + w * 8 + j;
            const float4* src = (const float4*)(queue + (size_t)sidx[r] * 256);
            float4 v = src[lane];
            float ss = v.x * v.x + v.y * v.y + v.z * v.z + v.w * v.w;
#pragma unroll
            for (int off = 1; off < 64; off <<= 1) ss += __shfl_xor(ss, off);
            float inv = 1.f / fmaxf(sqrtf(ss), 1e-12f);
            unsigned short o[4] = { f2bf(v.x * inv), f2bf(v.y * inv),
                                    f2bf(v.z * inv), f2bf(v.w * inv) };
            *(unsigned long long*)(negb + (size_t)r * 256 + lane * 4) =
                *(unsigned long long*)o;
        }
    } else {
        // -------- queue copy, cid in [0,1024), 4096 float4 each --------
        const int cid = id * 4 + (type - 1 - (type > 3));
        int base = cid * 4096 + t;
#pragma unroll
        for (int i = 0; i < 16; ++i)
            newq4[base + i * 256] = queue4[base + i * 256];
    }
}

// ---------------------------------------------------------------------------
// Projection GEMM: A=T12b [1024][1024] bf16, B=Wpt [256][1024] bf16 (NT),
// fp32 partials. BM=128 BN=64 BK=32, z = batch*NS + split (NS=4).
// ---------------------------------------------------------------------------
__global__ __launch_bounds__(256) void gemm_proj(const unsigned short* __restrict__ Ag,
                                                 const unsigned short* __restrict__ Bg,
                                                 float* __restrict__ Pg,
                                                 int No, int Ko, int nsplit,
                                                 long sAb) {
    __shared__ unsigned short As[128 * 32];
    __shared__ unsigned short Bs[64 * 32];
    const int z = blockIdx.z;
    const int batch = z / nsplit, split = z - batch * nsplit;
    const unsigned short* A = Ag + (long)batch * sAb;
    const unsigned short* B = Bg;
    float* P = Pg + (long)z * 1024 * No;
    const int Kc = Ko / nsplit, kbeg = split * Kc;
    const int row0 = blockIdx.y * 128, col0 = blockIdx.x * 64;
    const int t = threadIdx.x;
    const int lane = t & 63, wave = t >> 6;
    const int wr = wave >> 1, wc = wave & 1;
    const int lrow = lane & 15, quad = lane >> 4;

    floatx4 acc[4][2] = {};

    for (int kk = kbeg; kk < kbeg + Kc; kk += 32) {
        int c0 = t, c1 = t + 256;
        async_cp16(A + (size_t)(row0 + (c0 >> 2)) * Ko + kk + (c0 & 3) * 8,
                   (char*)As + (size_t)c0 * 16);
        async_cp16(A + (size_t)(row0 + (c1 >> 2)) * Ko + kk + (c1 & 3) * 8,
                   (char*)As + (size_t)c1 * 16);
        async_cp16(B + (size_t)(col0 + (t >> 2)) * Ko + kk + (t & 3) * 8,
                   (char*)Bs + (size_t)t * 16);
        __syncthreads();
        bf16x8 af[4], bf[2];
#pragma unroll
        for (int i = 0; i < 4; ++i)
            af[i] = *(const bf16x8*)(As + (size_t)(wr * 64 + i * 16 + lrow) * 32 + quad * 8);
#pragma unroll
        for (int j = 0; j < 2; ++j)
            bf[j] = *(const bf16x8*)(Bs + (size_t)(wc * 32 + j * 16 + lrow) * 32 + quad * 8);
#pragma unroll
        for (int i = 0; i < 4; ++i)
#pragma unroll
            for (int j = 0; j < 2; ++j)
                acc[i][j] = __builtin_amdgcn_mfma_f32_16x16x32_bf16(af[i], bf[j], acc[i][j], 0, 0, 0);
        __syncthreads();
    }
#pragma unroll
    for (int i = 0; i < 4; ++i) {
        int grow = row0 + wr * 64 + i * 16 + quad * 4;
#pragma unroll
        for (int j = 0; j < 2; ++j) {
            int gcol = col0 + wc * 32 + j * 16 + lrow;
#pragma unroll
            for (int r = 0; r < 4; ++r)
                P[(size_t)(grow + r) * No + gcol] = acc[i][j][r];
        }
    }
}

// reduce proj partials + l2norm + bf16 cast + pos/sumexp + scatter k rows.
// P layout: [2*nsplit][B][256] (q: 0..ns-1, k: ns..2ns-1). One block/row.
__global__ __launch_bounds__(256) void qk_finalize(const float* __restrict__ P,
                                                   const int* __restrict__ widx,
                                                   unsigned short* __restrict__ qkb,
                                                   float* __restrict__ newq,
                                                   float* __restrict__ pos,
                                                   float* __restrict__ sumexp,
                                                   int B_, int nsplit, float invT) {
    const int i = blockIdx.x, t = threadIdx.x;
    const long RM = (long)B_ * 256;
    float sq = 0.f, sk = 0.f;
    for (int s = 0; s < nsplit; ++s) {
        sq += P[(long)s * RM + (long)i * 256 + t];
        sk += P[(long)(nsplit + s) * RM + (long)i * 256 + t];
    }
    __shared__ float r0[256], r1[256], r2[256];
    r0[t] = sq * sq; r1[t] = sk * sk; r2[t] = sq * sk;
    __syncthreads();
    for (int off = 128; off > 0; off >>= 1) {
        if (t < off) { r0[t] += r0[t + off]; r1[t] += r1[t + off]; r2[t] += r2[t + off]; }
        __syncthreads();
    }
    float nq = fmaxf(sqrtf(r0[0]), 1e-12f);
    float nk = fmaxf(sqrtf(r1[0]), 1e-12f);
    float qn = sq / nq, kn = sk / nk;
    qkb[(size_t)i * 256 + t] = f2bf(qn);
    qkb[(size_t)(B_ + i) * 256 + t] = f2bf(kn);
    newq[(size_t)widx[i] * 256 + t] = kn;
    if (t == 0) {
        float p = (r2[0] / (nq * nk)) * invT;
        pos[i] = p;
        sumexp[i] = __expf(p);
    }
}

// ---------------------------------------------------------------------------
// Fused logits GEMM: q [B][256] bf16, neg [NNEG][256] bf16 (NT), BK=64,
// epilogue exp(acc/T) -> row-sum -> atomicAdd sumexp.
// ---------------------------------------------------------------------------
__global__ __launch_bounds__(256) void gemm_logits(const unsigned short* __restrict__ A,
                                                   const unsigned short* __restrict__ B,
                                                   float* __restrict__ sumexp,
                                                   int Ko, float invT) {
    __shared__ unsigned short As[128 * 64];
    __shared__ unsigned short Bs[128 * 64];
    __shared__ float rowred[128];
    const int row0 = blockIdx.y * 128, col0 = blockIdx.x * 128;
    const int t = threadIdx.x;
    const int lane = t & 63, wave = t >> 6;
    const int wr = wave >> 1, wc = wave & 1;
    const int lrow = lane & 15, quad = lane >> 4;

    floatx4 acc[4][4] = {};

    for (int kk = 0; kk < Ko; kk += 64) {
#pragma unroll
        for (int r = 0; r < 4; ++r) {
            int c = t + r * 256;
            async_cp16(A + (size_t)(row0 + (c >> 3)) * Ko + kk + (c & 7) * 8,
                       (char*)As + (size_t)c * 16);
            async_cp16(B + (size_t)(col0 + (c >> 3)) * Ko + kk + (c & 7) * 8,
                       (char*)Bs + (size_t)c * 16);
        }
        __syncthreads();
        bf16x8 af[4][2], bf[4][2];
#pragma unroll
        for (int i = 0; i < 4; ++i)
#pragma unroll
            for (int k2 = 0; k2 < 2; ++k2) {
                af[i][k2] = *(const bf16x8*)(As + (size_t)(wr * 64 + i * 16 + lrow) * 64 + k2 * 32 + quad * 8);
                bf[i][k2] = *(const bf16x8*)(Bs + (size_t)(wc * 64 + i * 16 + lrow) * 64 + k2 * 32 + quad * 8);
            }
#pragma unroll
        for (int k2 = 0; k2 < 2; ++k2)
#pragma unroll
            for (int i = 0; i < 4; ++i)
#pragma unroll
                for (int j = 0; j < 4; ++j)
                    acc[i][j] = __builtin_amdgcn_mfma_f32_16x16x32_bf16(af[i][k2], bf[j][k2], acc[i][j], 0, 0, 0);
        __syncthreads();
    }
    if (t < 128) rowred[t] = 0.f;
    __syncthreads();
#pragma unroll
    for (int i = 0; i < 4; ++i) {
#pragma unroll
        for (int r = 0; r < 4; ++r) {
            float s = 0.f;
#pragma unroll
            for (int j = 0; j < 4; ++j) s += __expf(acc[i][j][r] * invT);
            s += __shfl_xor(s, 1); s += __shfl_xor(s, 2);
            s += __shfl_xor(s, 4); s += __shfl_xor(s, 8);
            if (lrow == 0) atomicAdd(&rowred[wr * 64 + i * 16 + quad * 4 + r], s);
        }
    }
    __syncthreads();
    if (t < 128) atomicAdd(&sumexp[row0 + t], rowred[t]);
}

__global__ __launch_bounds__(256) void final_loss(const float* __restrict__ pos,
                                                  const float* __restrict__ sumexp,
                                                  float* __restrict__ out, int B_) {
    const int t = threadIdx.x;
    float acc = 0.f;
    for (int i = t; i < B_; i += 256) acc += logf(sumexp[i]) - pos[i];
    __shared__ float s[256];
    s[t] = acc;
    __syncthreads();
    for (int off = 128; off > 0; off >>= 1) {
        if (t < off) s[t] += s[t + off];
        __syncthreads();
    }
    if (t == 0) out[0] = s[0] / (float)B_;
}

extern "C" void kernel_launch(void* const* d_in, const int* in_sizes, int n_in,
                              void* d_out, int out_size, void* d_ws, size_t ws_size,
                              hipStream_t stream) {
    const float* y1    = (const float*)d_in[0];
    const float* y2    = (const float*)d_in[1];
    const float* Wq    = (const float*)d_in[2];
    const float* Wk    = (const float*)d_in[3];
    const float* Wp    = (const float*)d_in[4];
    const float* queue = (const float*)d_in[5];
    const int*   sidx  = (const int*)d_in[6];
    const int*   widx  = (const int*)d_in[7];
    float* out = (float*)d_out;

    const int B    = in_sizes[7];              // 1024
    const int NNEG = in_sizes[6];              // 16384
    const int D    = in_sizes[0] / B;          // 2048
    const int H    = in_sizes[2] / D;          // 1024
    const int M    = in_sizes[4] / H;          // 256
    const int Q    = in_sizes[5] / M;          // 65536
    const float invT = 1.0f / 0.07f;
    const int NS_P = 4;

    // ---- workspace layout ----
    float* ws  = (float*)d_ws;
    float* Pp     = ws;                              // [2*NS_P][B*M] = 2M floats
    float* pos    = Pp + (size_t)2 * NS_P * B * M;
    float* sumexp = pos + B;
    unsigned short* us = (unsigned short*)(sumexp + B);
    unsigned short* y2b  = us;                       // B*D   (y2b|y1b contiguous)
    unsigned short* y1b  = y2b + (size_t)B * D;      // B*D
    unsigned short* Wqt  = y1b + (size_t)B * D;      // H*D   (Wqt|Wkt contiguous)
    unsigned short* Wkt  = Wqt + (size_t)H * D;      // H*D
    unsigned short* Wpt  = Wkt + (size_t)H * D;      // M*H
    unsigned short* T12b = Wpt + (size_t)M * H;      // 2*B*H
    unsigned short* qkb  = T12b + (size_t)2 * B * H; // 2*B*M
    unsigned short* negb = qkb + (size_t)2 * B * M;  // NNEG*M

    // 1. casts + weight transposes
    const int nPrep = 2 * 1024 + 2 * (D / 32) * (H / 32) + (H / 32) * (M / 32);
    prep_small<<<nPrep, 256, 0, stream>>>(y2, y1, y2b, y1b, Wq, Wk, Wp,
                                          Wqt, Wkt, Wpt, D, H, M);

    // 2. encoder GEMM + queue copy + gather, one heterogeneous dispatch
    enc_plus<<<1792, 256, 0, stream>>>(y2b, Wqt, T12b,
                                       (const float4*)queue, (float4*)(out + 1),
                                       queue, sidx, negb);

    // 3. projection GEMMs -> fp32 partials (z = 2 batches x NS_P splits)
    gemm_proj<<<dim3(M / 64, B / 128, 2 * NS_P), 256, 0, stream>>>(
        T12b, Wpt, Pp, M, H, NS_P, (long)B * H);

    // 4. fused reduce + l2norm + cast + pos/sumexp + scatter k
    qk_finalize<<<B, 256, 0, stream>>>(Pp, widx, qkb, out + 1, pos, sumexp,
                                       B, NS_P, invT);

    // 5. fused negative logits + exp + row-sum
    gemm_logits<<<dim3(NNEG / 128, B / 128), 256, 0, stream>>>(
        qkb, negb, sumexp, M, invT);

    // 6. loss
    final_loss<<<1, 256, 0, stream>>>(pos, sumexp, out, B);
}